// Round 6
// baseline (201.703 us; speedup 1.0000x reference)
//
#include <hip/hip_runtime.h>

#define HH 256
#define NPIX (HH * HH)
#define TOPK 200
#define MIN_COUNT 400
#define FOCAL 221.0f

// Workspace layout per image (float offsets), stride 8704 floats (34 KB):
//   [0    .. 4096): colPartW[16][256]  (float) — one set per (block p, wave w)
//   [4096 .. 8192): colPartC[16][256]  (int)
//   [8192 .. 8448): rowW[256]          (float)
//   [8448 .. 8704): rowC[256]          (int)
#define WS_STRIDE 8704
#define WS_CPC    4096
#define WS_RW     8192
#define WS_RC     8448

// ---------------------------------------------------------------------------
// Kernel A: streaming histogram. 4 blocks per image, 256 threads (4 waves).
// Block p of image b owns rows [p*64, p*64+64). Per iteration each wave covers
// exactly one row (row_local = 4*i + wave, col = 4*lane + j). No cross-lane
// float reduction in the hot loop: row partials -> LDS, reduced once at end.
// ---------------------------------------------------------------------------
__global__ void mask2cube_hist(const float* __restrict__ x,
                               float* __restrict__ ws) {
    const int blk  = blockIdx.x;
    const int b    = blk >> 2;
    const int p    = blk & 3;
    const int t    = threadIdx.x;
    const int wave = t >> 6;
    const int lane = t & 63;

    const float4* __restrict__ xv =
        (const float4*)(x + (size_t)b * NPIX) + p * 4096;

    __shared__ float rowPartW[64][67];  // [row_local][lane], pad 67: conflict-free
    __shared__ int   rowCnt[64];

    float cW0 = 0.f, cW1 = 0.f, cW2 = 0.f, cW3 = 0.f;
    int   cC0 = 0,   cC1 = 0,   cC2 = 0,   cC3 = 0;

    #pragma unroll
    for (int mac = 0; mac < 4; ++mac) {
        float4 v0 = xv[(mac * 4 + 0) * 256 + t];   // 4 loads in flight
        float4 v1 = xv[(mac * 4 + 1) * 256 + t];
        float4 v2 = xv[(mac * 4 + 2) * 256 + t];
        float4 v3 = xv[(mac * 4 + 3) * 256 + t];
        #pragma unroll
        for (int u = 0; u < 4; ++u) {
            float4 v = (u == 0) ? v0 : (u == 1) ? v1 : (u == 2) ? v2 : v3;
            const int i = mac * 4 + u;
            bool m0 = v.x > 0.5f, m1 = v.y > 0.5f;
            bool m2 = v.z > 0.5f, m3 = v.w > 0.5f;
            float w0 = m0 ? v.x : 0.f, w1 = m1 ? v.y : 0.f;
            float w2 = m2 ? v.z : 0.f, w3 = m3 ? v.w : 0.f;
            cW0 += w0; cW1 += w1; cW2 += w2; cW3 += w3;
            cC0 += m0; cC1 += m1; cC2 += m2; cC3 += m3;
            // row partial: defer the float reduce to the end (LDS batch)
            rowPartW[4 * i + wave][lane] = (w0 + w1) + (w2 + w3);
            // count: scalar pipe only (ballot + popc)
            int cnt = __popcll(__ballot(m0)) + __popcll(__ballot(m1))
                    + __popcll(__ballot(m2)) + __popcll(__ballot(m3));
            if (lane == 0) rowCnt[4 * i + wave] = cnt;
        }
    }
    __syncthreads();

    float* wsb = ws + (size_t)b * WS_STRIDE;

    // reduce row partials: thread t -> row r = t>>2, quarter q = t&3
    {
        const int r = t >> 2, q = t & 3;
        float s = 0.f;
        #pragma unroll
        for (int j = 0; j < 16; ++j) s += rowPartW[r][q * 16 + j];
        s += __shfl_xor(s, 1, 64);
        s += __shfl_xor(s, 2, 64);
        if (q == 0) {
            wsb[WS_RW + p * 64 + r]          = s;
            ((int*)wsb)[WS_RC + p * 64 + r]  = rowCnt[r];
        }
    }

    // per-wave column partials straight to workspace (set index = p*4 + wave)
    {
        const int set = p * 4 + wave;
        ((float4*)&wsb[set * 256 + 4 * lane])[0] = make_float4(cW0, cW1, cW2, cW3);
        ((int4*)&((int*)wsb)[WS_CPC + set * 256 + 4 * lane])[0] =
            make_int4(cC0, cC1, cC2, cC3);
    }
}

// ---------------------------------------------------------------------------
// Kernel B: finish. One 256-thread block per image: combine partials, prefix
// scans, boundary detection, exact tie-break on the 4 boundary lines, output.
// ---------------------------------------------------------------------------
__device__ __forceinline__ float waveReduceSumF(float v) {
    #pragma unroll
    for (int off = 32; off > 0; off >>= 1)
        v += __shfl_xor(v, off, 64);
    return v;
}

__global__ void mask2cube_finish(const float* __restrict__ x,
                                 const float* __restrict__ ws,
                                 float* __restrict__ out) {
    const int b    = blockIdx.x;
    const int t    = threadIdx.x;
    const int wave = t >> 6;
    const int lane = t & 63;
    const float* __restrict__ xb  = x + (size_t)b * NPIX;
    const float* __restrict__ wsb = ws + (size_t)b * WS_STRIDE;

    __shared__ float rowW[HH];
    __shared__ int   rowC[HH];
    __shared__ float rowWC[HH];
    __shared__ float colW[HH];
    __shared__ int   colC[HH];
    __shared__ float colWC[HH];
    __shared__ float bN[4], bD[4];
    __shared__ int   bCoord[4], bR[4];
    __shared__ float partF[4];
    __shared__ int   partI[4];

    // combine the 16 column-partial sets; load row totals
    {
        float w = 0.f; int c = 0;
        #pragma unroll
        for (int s = 0; s < 16; ++s) {
            w += wsb[s * 256 + t];
            c += ((const int*)wsb)[WS_CPC + s * 256 + t];
        }
        colW[t]  = w;
        colC[t]  = c;
        colWC[t] = w * (float)t;
        float rw = wsb[WS_RW + t];
        rowW[t]  = rw;
        rowC[t]  = ((const int*)wsb)[WS_RC + t];
        rowWC[t] = rw * (float)t;
    }
    __syncthreads();

    // inclusive prefix scans over the 256 bins
    #pragma unroll 1
    for (int s = 1; s < HH; s <<= 1) {
        int   cc = 0, rc = 0;
        float cw = 0.f, cwc = 0.f, rw = 0.f, rwc = 0.f;
        if (t >= s) {
            cc  = colC[t - s];  cw  = colW[t - s];  cwc = colWC[t - s];
            rc  = rowC[t - s];  rw  = rowW[t - s];  rwc = rowWC[t - s];
        }
        __syncthreads();
        if (t >= s) {
            colC[t] += cc;  colW[t] += cw;  colWC[t] += cwc;
            rowC[t] += rc;  rowW[t] += rw;  rowWC[t] += rwc;
        }
        __syncthreads();
    }

    const int   totalC = colC[HH - 1];
    const float totW   = colW[HH - 1];
    const float totWC  = colWC[HH - 1];
    const float totWCr = rowWC[HH - 1];

    if (totalC <= MIN_COUNT) {   // invalid image -> zeros (uniform branch)
        if (t < 7) out[b * 7 + t] = 0.f;
        return;
    }

    // boundary detection
    {
        int   Pc   = colC[t];
        int   Pcm1 = t ? colC[t - 1] : 0;
        float wP   = colW[t],  wcP   = colWC[t];
        float wPm1 = t ? colW[t - 1]  : 0.f;
        float wcPm1= t ? colWC[t - 1] : 0.f;
        if (Pcm1 < TOPK && Pc >= TOPK) {                      // x_min (k=1)
            bCoord[1] = t; bR[1] = TOPK - Pcm1; bN[1] = wcPm1; bD[1] = wPm1;
        }
        if ((totalC - Pc) < TOPK && (totalC - Pcm1) >= TOPK) { // x_max (k=0)
            bCoord[0] = t; bR[0] = TOPK - (totalC - Pc);
            bN[0] = totWC - wcP; bD[0] = totW - wP;
        }
        int   Rc   = rowC[t];
        int   Rcm1 = t ? rowC[t - 1] : 0;
        float rwP  = rowW[t],  rwcP  = rowWC[t];
        float rwPm1 = t ? rowW[t - 1]  : 0.f;
        float rwcPm1= t ? rowWC[t - 1] : 0.f;
        if (Rcm1 < TOPK && Rc >= TOPK) {                      // y_min (k=3)
            bCoord[3] = t; bR[3] = TOPK - Rcm1; bN[3] = rwcPm1; bD[3] = rwPm1;
        }
        if ((totalC - Rc) < TOPK && (totalC - Rcm1) >= TOPK) { // y_max (k=2)
            bCoord[2] = t; bR[2] = TOPK - (totalC - Rc);
            bN[2] = totWCr - rwcP; bD[2] = totW - rwP;
        }
    }
    __syncthreads();

    // boundary-line partial sums (exact tie-break, order = flat index)
    float means[4];
    #pragma unroll
    for (int k = 0; k < 4; ++k) {
        const int cs = bCoord[k];
        const int r  = bR[k];
        // k<2: boundary column cs, order = increasing y; k>=2: row cs, incr. x
        float w = (k < 2) ? xb[(size_t)t * HH + cs] : xb[(size_t)cs * HH + t];
        bool m = w > 0.5f;
        unsigned long long bal = __ballot(m);
        int lanePfx = __popcll(bal & ((1ull << lane) - 1ull));
        int wTot    = __popcll(bal);
        if (lane == 0) partI[wave] = wTot;
        __syncthreads();
        int wOff = 0;
        #pragma unroll
        for (int ww = 0; ww < 4; ++ww)
            if (ww < wave) wOff += partI[ww];
        int pfx = wOff + lanePfx;
        float sel = (m && (pfx < r)) ? w : 0.f;
        float sr = waveReduceSumF(sel);
        if (lane == 0) partF[wave] = sr;
        __syncthreads();
        float part = (partF[0] + partF[1]) + (partF[2] + partF[3]);
        means[k] = (bN[k] + part * (float)cs) / (bD[k] + part);
        __syncthreads();
    }

    // final 7-vector
    if (t == 0) {
        float x_maxw = means[0], x_minw = means[1];
        float y_maxw = means[2], y_minw = means[3];
        float y_min = 255.0f - y_maxw;
        float y_max = 255.0f - y_minw;
        float z = 1.0f + y_min / 128.0f;
        float xm = x_minw - 128.0f;
        float xM = x_maxw - 128.0f;
        float x3min = xm / FOCAL / z;
        float x3max = xM / FOCAL / z;
        float y3min = y_min / FOCAL / z;
        float y3max = y_max / FOCAL / z;
        float* o = out + b * 7;
        o[0] = (x3max + x3min) * 0.5f;
        o[1] = (y3max + y3min) * 0.5f;
        o[2] = z;
        o[3] = (x3max - x3min) * 0.5f;
        o[4] = (y3max - y3min) * 0.5f;
        o[5] = 0.1f;
        o[6] = 0.0f;
    }
}

extern "C" void kernel_launch(void* const* d_in, const int* in_sizes, int n_in,
                              void* d_out, int out_size, void* d_ws, size_t ws_size,
                              hipStream_t stream) {
    const float* x = (const float*)d_in[0];
    float* out = (float*)d_out;
    float* ws  = (float*)d_ws;
    const int B = in_sizes[0] / NPIX;
    mask2cube_hist<<<B * 4, 256, 0, stream>>>(x, ws);
    mask2cube_finish<<<B, 256, 0, stream>>>(x, ws, out);
}